// Round 4
// baseline (145.796 us; speedup 1.0000x reference)
//
#include <hip/hip_runtime.h>
#include <hip/hip_bf16.h>

// Problem geometry (fixed by the reference)
#define BD   4
#define SD   8
#define LSEC 256
#define LL   254
#define DD   768
#define MAXS 100
#define TT   (SD*LL)   // 2032

// Flat output offsets (float32 elements, reference return order)
#define OFF_SF  0LL                       // sentence_feature [4,100,768]
#define OFF_TM  307200LL                  // tran_mask        [4,2032,8]
#define OFF_TMS 372224LL                  // tran_mask_sec    [4,100,8]
#define OFF_SMF 375424LL                  // sentence_mask_full [4,2032,2032]
#define OFF_SEC (375424LL + 16516096LL)   // section_mask_full  [4,2032,2032]
#define OFF_LOG 33407616LL                // logits1 [4,2]

// K1 block partition: gemm first (latency-bound, start early), prep, then mask
#define NGEMM 300                 // 25 row-tiles x 12 col-tiles (16x64)
#define NPREP BD
#define MASKBASE (NGEMM + NPREP)
#define NMASK 1024                // 32 sections x 32 row-chunks (8 rows each)
#define NW 65                     // diagonal-window float4s per row (260 cols)

typedef float f4 __attribute__((ext_vector_type(4)));

__device__ __forceinline__ void nts(float* p, f4 v) {
    __builtin_nontemporal_store(v, (f4*)p);
}

// ---------------------------------------------------------------------------
// K0: per-(sentence, d-chunk) max pooling; block finds its own range.
// ---------------------------------------------------------------------------
__global__ __launch_bounds__(256) void pool_kernel(
    const float* __restrict__ atf,     // [32][256][768]
    const int*   __restrict__ ids_g,   // [B][T], nondecreasing runs 1..100
    float* __restrict__ pooled)        // [400][768] ws
{
    const int p    = blockIdx.x;
    const int sent = p % (BD*MAXS);
    const int d0   = (p / (BD*MAXS)) << 8;   // 0,256,512
    const int b    = sent / MAXS;
    const int sid  = sent % MAXS + 1;
    const int tid  = threadIdx.x;

    __shared__ int sf, sl;
    if (tid == 0) { sf = TT; sl = -1; }
    __syncthreads();
    int lf = TT, lm = -1;
    for (int t = tid; t < TT; t += 256) {
        if (ids_g[b*TT + t] == sid) { lf = min(lf, t); lm = max(lm, t); }
    }
    atomicMin(&sf, lf);
    atomicMax(&sl, lm);
    __syncthreads();
    const int f = sf, l = sl;

    float m = 0.0f;                    // absent sentence id -> zero
    if (l >= 0) {
        float m0 = -INFINITY, m1 = -INFINITY, m2 = -INFINITY, m3 = -INFINITY;
        for (int t = f; t <= l; t += 4) {
            int t1 = min(t + 1, l), t2 = min(t + 2, l), t3 = min(t + 3, l);
            long long r0 = ((long long)(b*SD + t  / LL) * LSEC + 1 + t  % LL) * DD + d0 + tid;
            long long r1 = ((long long)(b*SD + t1 / LL) * LSEC + 1 + t1 % LL) * DD + d0 + tid;
            long long r2 = ((long long)(b*SD + t2 / LL) * LSEC + 1 + t2 % LL) * DD + d0 + tid;
            long long r3 = ((long long)(b*SD + t3 / LL) * LSEC + 1 + t3 % LL) * DD + d0 + tid;
            m0 = fmaxf(m0, atf[r0]);
            m1 = fmaxf(m1, atf[r1]);
            m2 = fmaxf(m2, atf[r2]);
            m3 = fmaxf(m3, atf[r3]);
        }
        m = fmaxf(fmaxf(m0, m1), fmaxf(m2, m3));
    }
    pooled[(long long)sent * DD + d0 + tid] = m;
}

// ---------------------------------------------------------------------------
// K1: gemm(16x64 tiles) + prep + mask(zero/window split), one dispatch
// ---------------------------------------------------------------------------
union K1S {
    struct { float As[16][68]; float Ws[64][68]; } g;                  // 21760 B
    struct { int ids[TT]; int cnt[SD]; int st[SD]; float red[256]; } p;
    struct { int ids[LL]; float am[LL]; } m;
};

__global__ __launch_bounds__(256, 4) void k1_kernel(
    const float* __restrict__ pf,      // pooled_feature [32][768]
    const int*   __restrict__ att,     // [32][256]
    const int*   __restrict__ ids_g,   // [B][T]
    const float* __restrict__ Wg2,     // [768][768] row-major [e][d]
    const float* __restrict__ Wcls,    // [2][768]
    const float* __restrict__ bcls,    // [2]
    const float* __restrict__ pooled,  // [400][768] ws
    float* __restrict__ out)
{
    __shared__ K1S sm;
    const int blk = blockIdx.x;
    const int tid = threadIdx.x;

    if (blk < NGEMM) {
        // -------- gemm: out_sf[r][e] = sum_d pooled[r][d]*Wg2[e][d] --------
        const int r0 = (blk % 25) * 16;
        const int e0 = (blk / 25) * 64;
        const int er = tid & 63;       // col within tile
        const int sr = tid >> 6;       // 0..3 (wave id) -> rows 4sr..4sr+3
        float acc[4] = {0.f, 0.f, 0.f, 0.f};

        for (int k0 = 0; k0 < DD; k0 += 64) {
            {   // stage A: 16x64 floats = 256 f4
                int i = tid >> 4, c4 = (tid & 15) * 4;
                *(f4*)&sm.g.As[i][c4] = *(const f4*)&pooled[(long long)(r0 + i)*DD + k0 + c4];
            }
            #pragma unroll
            for (int it = 0; it < 4; ++it) {   // stage W: 64x64 floats = 1024 f4
                int idx = tid + it*256;
                int row = idx >> 4, c4 = (idx & 15) * 4;
                *(f4*)&sm.g.Ws[row][c4] = *(const f4*)&Wg2[(long long)(e0 + row)*DD + k0 + c4];
            }
            __syncthreads();
            #pragma unroll
            for (int k = 0; k < 64; k += 4) {
                f4 w = *(f4*)&sm.g.Ws[er][k];
                #pragma unroll
                for (int rr = 0; rr < 4; ++rr) {
                    f4 a = *(f4*)&sm.g.As[4*sr + rr][k];   // wave-uniform -> broadcast
                    acc[rr] += a.x*w.x + a.y*w.y + a.z*w.z + a.w*w.w;
                }
            }
            __syncthreads();
        }
        #pragma unroll
        for (int rr = 0; rr < 4; ++rr)
            out[OFF_SF + (long long)(r0 + 4*sr + rr)*DD + e0 + er] = acc[rr];
    } else if (blk < MASKBASE) {
        // -------- prep: tran_mask_sec + tran_mask + logits1 for doc b ------
        const int b = blk - NGEMM;
        for (int t = tid; t < TT; t += 256) sm.p.ids[t] = ids_g[b*TT + t];
        if (tid < SD) sm.p.cnt[tid] = 0;
        __syncthreads();
        for (int t = tid; t < TT; t += 256) {
            int j = t / LL;
            bool bnd = (t % LL == 0) || (sm.p.ids[t] != sm.p.ids[t-1]);
            if (bnd) atomicAdd(&sm.p.cnt[j], 1);
        }
        __syncthreads();
        if (tid == 0) {
            int acc = 0;
            for (int j = 0; j < SD; ++j) { sm.p.st[j] = acc; acc += sm.p.cnt[j]; }
        }
        __syncthreads();
        for (int idx = tid; idx < MAXS*SD; idx += 256) {
            int r = idx / SD, j = idx % SD;
            float v = (r >= sm.p.st[j] && r < sm.p.st[j] + sm.p.cnt[j]) ? 1.0f : 0.0f;
            out[OFF_TMS + (long long)b*(MAXS*SD) + idx] = v;
        }
        // tran_mask rows for this doc: [T][8], f4 stores
        for (int idx = tid; idx < TT*2; idx += 256) {
            int row = idx >> 1, h = idx & 1;
            int j1 = row / LL;
            f4 v;
            v.x = (4*h + 0 == j1) ? 1.f : 0.f;
            v.y = (4*h + 1 == j1) ? 1.f : 0.f;
            v.z = (4*h + 2 == j1) ? 1.f : 0.f;
            v.w = (4*h + 3 == j1) ? 1.f : 0.f;
            nts((float*)(out + OFF_TM + ((long long)b*TT + row)*SD + 4*h), v);
        }
        // logits1
        float acc0 = 0.f, acc1 = 0.f;
        #pragma unroll
        for (int k = 0; k < 3; ++k) {
            int d = tid + k*256;
            float mv = pf[(b*SD)*DD + d];
            #pragma unroll
            for (int j = 1; j < SD; ++j) mv = fmaxf(mv, pf[(b*SD + j)*DD + d]);
            acc0 += mv * Wcls[d];
            acc1 += mv * Wcls[DD + d];
        }
        sm.p.red[tid] = acc0; __syncthreads();
        for (int off = 128; off > 0; off >>= 1) { if (tid < off) sm.p.red[tid] += sm.p.red[tid+off]; __syncthreads(); }
        float l0 = sm.p.red[0];
        __syncthreads();
        sm.p.red[tid] = acc1; __syncthreads();
        for (int off = 128; off > 0; off >>= 1) { if (tid < off) sm.p.red[tid] += sm.p.red[tid+off]; __syncthreads(); }
        if (tid == 0) {
            out[OFF_LOG + b*2 + 0] = l0          + bcls[0];
            out[OFF_LOG + b*2 + 1] = sm.p.red[0] + bcls[1];
        }
    } else {
        // -------- mask: 8 rows of both big masks for (b, j1, chunk) --------
        const int idx0  = blk - MASKBASE;    // 0..1023
        const int sec   = idx0 >> 5;         // 0..31
        const int chunk = idx0 & 31;         // 0..31 (8 rows each)
        const int b  = sec >> 3;
        const int j1 = sec & 7;
        for (int i = tid; i < LL; i += 256) {
            sm.m.ids[i] = ids_g[b*TT + j1*LL + i];
            sm.m.am[i]  = (float)att[(b*SD + j1)*LSEC + 1 + i];
        }
        __syncthreads();
        const int cstart = j1 * LL;
        const int wlo4   = cstart >> 2;      // first f4 of diagonal window
        const f4 z4 = {0.f, 0.f, 0.f, 0.f};

        // Phase A: pure-zero f4 stores everywhere outside the window
        #pragma unroll
        for (int rr = 0; rr < 8; ++rr) {
            const int i1 = chunk*8 + rr;
            if (i1 >= LL) break;
            float* row4 = out + OFF_SMF + ((long long)b*TT + cstart + i1) * TT;
            float* row5 = row4 + (OFF_SEC - OFF_SMF);
            #pragma unroll
            for (int h = 0; h < 2; ++h) {
                int c4i = tid + h*256;
                if (c4i >= TT/4) break;
                if (c4i >= wlo4 && c4i < wlo4 + NW) continue;
                nts(row4 + c4i*4, z4);
                nts(row5 + c4i*4, z4);
            }
        }
        // Phase B: computed window f4s (8 rows x NW), LDS compare logic
        for (int idx = tid; idx < 8*NW; idx += 256) {
            int rr = idx / NW, u = idx % NW;
            int i1 = chunk*8 + rr;
            if (i1 >= LL) continue;
            int c4i = wlo4 + u;
            if (c4i >= TT/4) continue;
            int c = c4i * 4;
            const int   myid = sm.m.ids[i1];
            const float am1  = sm.m.am[i1];
            f4 v4, v5;
            float* pv4 = (float*)&v4; float* pv5 = (float*)&v5;
            #pragma unroll
            for (int uu = 0; uu < 4; ++uu) {
                int i2 = c + uu - cstart;
                bool in = (i2 >= 0) & (i2 < LL);
                int ii = in ? i2 : 0;
                pv4[uu] = in ? ((sm.m.ids[ii] == myid) ? 1.f : 0.f) : 0.f;
                pv5[uu] = in ? (sm.m.am[ii] * am1) : 0.f;
            }
            float* row4 = out + OFF_SMF + ((long long)b*TT + cstart + i1) * TT;
            float* row5 = row4 + (OFF_SEC - OFF_SMF);
            nts(row4 + c, v4);
            nts(row5 + c, v5);
        }
    }
}

// ---------------------------------------------------------------------------
extern "C" void kernel_launch(void* const* d_in, const int* in_sizes, int n_in,
                              void* d_out, int out_size, void* d_ws, size_t ws_size,
                              hipStream_t stream)
{
    const float* atf  = (const float*)d_in[0];  // all_token_feature [32,256,768]
    const float* pf   = (const float*)d_in[1];  // pooled_feature    [32,768]
    const int*   att  = (const int*)  d_in[2];  // attention_mask    [32,256]
    const int*   ids  = (const int*)  d_in[3];  // sentence_mask     [4,8,254]
    const float* Wg2  = (const float*)d_in[4];  // W_g2 [768,768]
    const float* Wcls = (const float*)d_in[5];  // W_cls [2,768]
    const float* bcls = (const float*)d_in[6];  // b_cls [2]
    float* out = (float*)d_out;

    float* pooled = (float*)d_ws;               // [400][768] = 1.23 MB

    hipLaunchKernelGGL(pool_kernel, dim3(BD*MAXS*3), dim3(256), 0, stream,
                       atf, ids, pooled);
    hipLaunchKernelGGL(k1_kernel, dim3(MASKBASE + NMASK), dim3(256), 0, stream,
                       pf, att, ids, Wg2, Wcls, bcls, pooled, out);
}

// Round 5
// 94.170 us; speedup vs baseline: 1.5482x; 1.5482x over previous
//
#include <hip/hip_runtime.h>
#include <hip/hip_bf16.h>

// Problem geometry (fixed by the reference)
#define BD   4
#define SD   8
#define LSEC 256
#define LL   254
#define DD   768
#define MAXS 100
#define TT   (SD*LL)   // 2032

// Flat output offsets (float32 elements, reference return order)
#define OFF_SF  0LL                       // sentence_feature [4,100,768]
#define OFF_TM  307200LL                  // tran_mask        [4,2032,8]
#define OFF_TMS 372224LL                  // tran_mask_sec    [4,100,8]
#define OFF_SMF 375424LL                  // sentence_mask_full [4,2032,2032]
#define OFF_SEC (375424LL + 16516096LL)   // section_mask_full  [4,2032,2032]
#define OFF_LOG 33407616LL                // logits1 [4,2]

#define NF4   8258048                     // (2*16516096)/4 f4s of both masks
// Dispatch 1: pool blocks then zerofill blocks
#define NPOOL (BD*MAXS*3)                 // 1200
#define NZERO 2048
// Dispatch 2: gemm, prep, window
#define NGEMM 300                         // 25 row-tiles x 12 col-tiles (16x64)
#define NPREP BD
#define WINBASE (NGEMM + NPREP)
#define NWIN  (BD*SD*16)                  // 32 sections x 16 row-chunks (16 rows)

typedef float f4 __attribute__((ext_vector_type(4)));

// ---------------------------------------------------------------------------
// K0: pool (producer for gemm) + zerofill of both big masks (132 MB)
// ---------------------------------------------------------------------------
__global__ __launch_bounds__(256) void k0_kernel(
    const float* __restrict__ atf,     // [32][256][768]
    const int*   __restrict__ ids_g,   // [B][T], nondecreasing runs 1..100
    float* __restrict__ pooled,        // [400][768] ws
    float* __restrict__ out)
{
    const int blk = blockIdx.x;
    const int tid = threadIdx.x;

    if (blk >= NPOOL) {
        // ---------- zerofill: pure fill-style f4 stores --------------------
        const int zblk = blk - NPOOL;
        f4* base = (f4*)(out + OFF_SMF);
        const f4 z4 = {0.f, 0.f, 0.f, 0.f};
        for (long long i = (long long)zblk*256 + tid; i < NF4; i += (long long)NZERO*256)
            base[i] = z4;
        return;
    }
    // ---------- pool: (sentence, d-chunk) max over contiguous range --------
    __shared__ int sf, sl;
    const int p    = blk;
    const int sent = p % (BD*MAXS);
    const int d0   = (p / (BD*MAXS)) << 8;   // 0,256,512
    const int b    = sent / MAXS;
    const int sid  = sent % MAXS + 1;

    if (tid == 0) { sf = TT; sl = -1; }
    __syncthreads();
    int lf = TT, lm = -1;
    for (int t = tid; t < TT; t += 256) {
        if (ids_g[b*TT + t] == sid) { lf = min(lf, t); lm = max(lm, t); }
    }
    atomicMin(&sf, lf);
    atomicMax(&sl, lm);
    __syncthreads();
    const int f = sf, l = sl;

    float m = 0.0f;                    // absent sentence id -> zero
    if (l >= 0) {
        float m0 = -INFINITY, m1 = -INFINITY, m2 = -INFINITY, m3 = -INFINITY;
        for (int t = f; t <= l; t += 4) {
            int t1 = min(t + 1, l), t2 = min(t + 2, l), t3 = min(t + 3, l);
            long long r0 = ((long long)(b*SD + t  / LL) * LSEC + 1 + t  % LL) * DD + d0 + tid;
            long long r1 = ((long long)(b*SD + t1 / LL) * LSEC + 1 + t1 % LL) * DD + d0 + tid;
            long long r2 = ((long long)(b*SD + t2 / LL) * LSEC + 1 + t2 % LL) * DD + d0 + tid;
            long long r3 = ((long long)(b*SD + t3 / LL) * LSEC + 1 + t3 % LL) * DD + d0 + tid;
            m0 = fmaxf(m0, atf[r0]);
            m1 = fmaxf(m1, atf[r1]);
            m2 = fmaxf(m2, atf[r2]);
            m3 = fmaxf(m3, atf[r3]);
        }
        m = fmaxf(fmaxf(m0, m1), fmaxf(m2, m3));
    }
    pooled[(long long)sent * DD + d0 + tid] = m;
}

// ---------------------------------------------------------------------------
// K1: gemm (16x64 tiles, swizzled Ws) + prep + diagonal-window rewrite
// ---------------------------------------------------------------------------
union K1S {
    struct { float As[16][68]; float Ws[64][64]; } g;                  // 20736 B
    struct { int ids[TT]; int cnt[SD]; int st[SD]; float red[256]; } p;
    struct { int sid[256]; float sam[256]; } w;
};

__global__ __launch_bounds__(256) void k1_kernel(
    const float* __restrict__ pf,      // pooled_feature [32][768]
    const int*   __restrict__ att,     // [32][256]
    const int*   __restrict__ ids_g,   // [B][T]
    const float* __restrict__ Wg2,     // [768][768] row-major [e][d]
    const float* __restrict__ Wcls,    // [2][768]
    const float* __restrict__ bcls,    // [2]
    const float* __restrict__ pooled,  // [400][768] ws
    float* __restrict__ out)
{
    __shared__ K1S sm;
    const int blk = blockIdx.x;
    const int tid = threadIdx.x;

    if (blk < NGEMM) {
        // -------- gemm: out_sf[r][e] = sum_d pooled[r][d]*Wg2[e][d] --------
        const int r0 = (blk % 25) * 16;
        const int e0 = (blk / 25) * 64;
        const int er = tid & 63;       // col within tile
        const int sr = tid >> 6;       // wave id 0..3 -> rows 4sr..4sr+3
        float acc[4] = {0.f, 0.f, 0.f, 0.f};

        for (int k0 = 0; k0 < DD; k0 += 64) {
            {   // stage A: 16x64 floats = 256 f4
                int i = tid >> 4, c4 = (tid & 15) * 4;
                *(f4*)&sm.g.As[i][c4] = *(const f4*)&pooled[(long long)(r0 + i)*DD + k0 + c4];
            }
            #pragma unroll
            for (int it = 0; it < 4; ++it) {   // stage W, XOR-swizzled f4 cols
                int idx = tid + it*256;
                int row = idx >> 4, k4 = idx & 15;
                *(f4*)&sm.g.Ws[row][((k4 ^ (row & 15)) << 2)] =
                    *(const f4*)&Wg2[(long long)(e0 + row)*DD + k0 + k4*4];
            }
            __syncthreads();
            #pragma unroll
            for (int k4r = 0; k4r < 16; ++k4r) {
                f4 w = *(f4*)&sm.g.Ws[er][((k4r ^ (er & 15)) << 2)];
                #pragma unroll
                for (int rr = 0; rr < 4; ++rr) {
                    f4 a = *(f4*)&sm.g.As[4*sr + rr][k4r*4];   // wave-uniform
                    acc[rr] += a.x*w.x + a.y*w.y + a.z*w.z + a.w*w.w;
                }
            }
            __syncthreads();
        }
        #pragma unroll
        for (int rr = 0; rr < 4; ++rr)
            out[OFF_SF + (long long)(r0 + 4*sr + rr)*DD + e0 + er] = acc[rr];
    } else if (blk < WINBASE) {
        // -------- prep: tran_mask_sec + tran_mask + logits1 for doc b ------
        const int b = blk - NGEMM;
        for (int t = tid; t < TT; t += 256) sm.p.ids[t] = ids_g[b*TT + t];
        if (tid < SD) sm.p.cnt[tid] = 0;
        __syncthreads();
        for (int t = tid; t < TT; t += 256) {
            int j = t / LL;
            bool bnd = (t % LL == 0) || (sm.p.ids[t] != sm.p.ids[t-1]);
            if (bnd) atomicAdd(&sm.p.cnt[j], 1);
        }
        __syncthreads();
        if (tid == 0) {
            int acc = 0;
            for (int j = 0; j < SD; ++j) { sm.p.st[j] = acc; acc += sm.p.cnt[j]; }
        }
        __syncthreads();
        for (int idx = tid; idx < MAXS*SD; idx += 256) {
            int r = idx / SD, j = idx % SD;
            float v = (r >= sm.p.st[j] && r < sm.p.st[j] + sm.p.cnt[j]) ? 1.0f : 0.0f;
            out[OFF_TMS + (long long)b*(MAXS*SD) + idx] = v;
        }
        for (int idx = tid; idx < TT*2; idx += 256) {
            int row = idx >> 1, h = idx & 1;
            int j1 = row / LL;
            f4 v;
            v.x = (4*h + 0 == j1) ? 1.f : 0.f;
            v.y = (4*h + 1 == j1) ? 1.f : 0.f;
            v.z = (4*h + 2 == j1) ? 1.f : 0.f;
            v.w = (4*h + 3 == j1) ? 1.f : 0.f;
            *(f4*)(out + OFF_TM + ((long long)b*TT + row)*SD + 4*h) = v;
        }
        float acc0 = 0.f, acc1 = 0.f;
        #pragma unroll
        for (int k = 0; k < 3; ++k) {
            int d = tid + k*256;
            float mv = pf[(b*SD)*DD + d];
            #pragma unroll
            for (int j = 1; j < SD; ++j) mv = fmaxf(mv, pf[(b*SD + j)*DD + d]);
            acc0 += mv * Wcls[d];
            acc1 += mv * Wcls[DD + d];
        }
        sm.p.red[tid] = acc0; __syncthreads();
        for (int off = 128; off > 0; off >>= 1) { if (tid < off) sm.p.red[tid] += sm.p.red[tid+off]; __syncthreads(); }
        float l0 = sm.p.red[0];
        __syncthreads();
        sm.p.red[tid] = acc1; __syncthreads();
        for (int off = 128; off > 0; off >>= 1) { if (tid < off) sm.p.red[tid] += sm.p.red[tid+off]; __syncthreads(); }
        if (tid == 0) {
            out[OFF_LOG + b*2 + 0] = l0          + bcls[0];
            out[OFF_LOG + b*2 + 1] = sm.p.red[0] + bcls[1];
        }
    } else {
        // -------- window: rewrite the 64-f4 diagonal window of 16 rows -----
        const int idx0  = blk - WINBASE;     // 0..511
        const int sec   = idx0 >> 4;         // 0..31
        const int chunk = idx0 & 15;         // 16 rows each
        const int b  = sec >> 3;
        const int j1 = sec & 7;
        const int cstart  = j1 * LL;
        const int wlo4    = cstart >> 2;
        const int sh      = cstart & 3;      // 0 or 2

        for (int k = tid; k < 256; k += 256) {
            int i2 = k - sh;
            bool v = (i2 >= 0) & (i2 < LL);
            sm.w.sid[k] = v ? ids_g[b*TT + cstart + i2] : -1;
            sm.w.sam[k] = v ? (float)att[(b*SD + j1)*LSEC + 1 + i2] : 0.f;
        }
        __syncthreads();

        #pragma unroll
        for (int it = 0; it < 4; ++it) {
            int idx = tid + it*256;          // 16 rows x 64 u
            int rr = idx >> 6, u = idx & 63;
            int i1 = chunk*16 + rr;
            if (i1 >= LL) continue;
            const int   myid = sm.w.sid[i1 + sh];
            const float am1  = sm.w.sam[i1 + sh];
            int4 s4 = *(int4*)&sm.w.sid[u*4];
            f4   a4 = *(f4*)  &sm.w.sam[u*4];
            f4 v4, v5;
            v4.x = (s4.x == myid) ? 1.f : 0.f;
            v4.y = (s4.y == myid) ? 1.f : 0.f;
            v4.z = (s4.z == myid) ? 1.f : 0.f;
            v4.w = (s4.w == myid) ? 1.f : 0.f;
            v5 = a4 * am1;
            float* row4 = out + OFF_SMF + ((long long)b*TT + cstart + i1) * TT + (wlo4 + u)*4;
            *(f4*)row4 = v4;
            *(f4*)(row4 + (OFF_SEC - OFF_SMF)) = v5;
        }
    }
}

// ---------------------------------------------------------------------------
extern "C" void kernel_launch(void* const* d_in, const int* in_sizes, int n_in,
                              void* d_out, int out_size, void* d_ws, size_t ws_size,
                              hipStream_t stream)
{
    const float* atf  = (const float*)d_in[0];  // all_token_feature [32,256,768]
    const float* pf   = (const float*)d_in[1];  // pooled_feature    [32,768]
    const int*   att  = (const int*)  d_in[2];  // attention_mask    [32,256]
    const int*   ids  = (const int*)  d_in[3];  // sentence_mask     [4,8,254]
    const float* Wg2  = (const float*)d_in[4];  // W_g2 [768,768]
    const float* Wcls = (const float*)d_in[5];  // W_cls [2,768]
    const float* bcls = (const float*)d_in[6];  // b_cls [2]
    float* out = (float*)d_out;

    float* pooled = (float*)d_ws;               // [400][768] = 1.23 MB

    hipLaunchKernelGGL(k0_kernel, dim3(NPOOL + NZERO), dim3(256), 0, stream,
                       atf, ids, pooled, out);
    hipLaunchKernelGGL(k1_kernel, dim3(WINBASE + NWIN), dim3(256), 0, stream,
                       pf, att, ids, Wg2, Wcls, bcls, pooled, out);
}